// Round 8
// baseline (127.751 us; speedup 1.0000x reference)
//
#include <hip/hip_runtime.h>

// Fused LSTM: B=4096, T=200, F=64, H=16, O=1.
// 128 blocks x 192 threads: wave0 = consumer with TWO interleaved 16-batch
// chains (ILP hides chain stalls deterministically); waves 1/2 = producers,
// one per batch-group.
//   pre^T(64x16) = Wih(64x64) @ x_t^T + Whh(64x16) @ h^T + bias
// Producers: input projection on MFMA (bias folded into C), 8 steps/chunk,
// writing gx f32x4 tiles into a per-group 2-deep LDS ring; x reloads for
// chunk i+1 are issued per-step DURING chunk i compute so the pre-barrier
// vmcnt drain is covered. Consumer: per step and per group, one
// mfma_16x16x16f16(WhhHi, hHi, gx) + lane-local cell update; gx prefetched
// one step ahead. Gate-type m = D-tile m, so each lane holds i,f,g,o of the
// SAME 4 (batch,unit) pairs and its h[4] is directly the next step's
// recurrence B-fragment -> zero cross-lane ops in the serial chain.

#define Bsz 4096
#define Tn  200
#define Fn  64
#define Hn  16
#define CS  8     // steps per chunk
#define NCH 25    // chunks (25*8 = 200)

typedef _Float16 half8  __attribute__((ext_vector_type(8)));
typedef _Float16 half4  __attribute__((ext_vector_type(4)));
typedef float    f32x4  __attribute__((ext_vector_type(4)));

__device__ __forceinline__ half8 to_half8(const float4& a, const float4& b) {
    half8 h;
    h[0] = (_Float16)a.x; h[1] = (_Float16)a.y; h[2] = (_Float16)a.z; h[3] = (_Float16)a.w;
    h[4] = (_Float16)b.x; h[5] = (_Float16)b.y; h[6] = (_Float16)b.z; h[7] = (_Float16)b.w;
    return h;
}

__device__ __forceinline__ float sigm(float z) {
    return __builtin_amdgcn_rcpf(1.0f + __builtin_amdgcn_exp2f(z * -1.4426950408889634f));
}
__device__ __forceinline__ float tanhp(float z) {
    return fmaf(2.0f, __builtin_amdgcn_rcpf(
        1.0f + __builtin_amdgcn_exp2f(z * -2.8853900817779268f)), -1.0f);
}

__global__ __launch_bounds__(192, 1) void lstm_fused(
    const float* __restrict__ x,     // [B, T, F]
    const float* __restrict__ Wih,   // [64, 64]
    const float* __restrict__ Whh,   // [64, 16]
    const float* __restrict__ bih,   // [64]
    const float* __restrict__ bhh,   // [64]
    const float* __restrict__ Wout,  // [1, 16]
    const float* __restrict__ bout,  // [1]
    float* __restrict__ out)         // [B, 1]
{
    const int lane  = threadIdx.x & 63;
    const int wave  = threadIdx.x >> 6;   // 0 = consumer, 1/2 = producers
    const int l15   = lane & 15;
    const int lhi   = lane >> 4;
    const int bbase = (int)blockIdx.x * 32;

    // gx rings: [group][buf][step][m][lane] f32x4 = 2*2*8*4*64*16 B = 128 KiB
    __shared__ f32x4 gxbuf[2][2][CS][4][64];

    // ================= producer-side state =================
    half8 WihF[4][2];
    f32x4 biasC[4];
    float4 xr[CS][4];                       // register stage, one chunk
    const int pg = (wave >= 1) ? (wave - 1) : 0;
    const float* xl = x + (size_t)(bbase + pg * 16 + l15) * (Tn * Fn) + lhi * 8;

    if (wave >= 1) {
#pragma unroll
        for (int m = 0; m < 4; ++m)
#pragma unroll
            for (int kh = 0; kh < 2; ++kh) {
                const float* wr = Wih + (m * 16 + l15) * Fn + kh * 32 + lhi * 8;
                float4 w0 = *reinterpret_cast<const float4*>(wr);
                float4 w1 = *reinterpret_cast<const float4*>(wr + 4);
                WihF[m][kh] = to_half8(w0, w1);
            }
#pragma unroll
        for (int m = 0; m < 4; ++m) {
            float4 v0 = *reinterpret_cast<const float4*>(bih + m * 16 + lhi * 4);
            float4 v1 = *reinterpret_cast<const float4*>(bhh + m * 16 + lhi * 4);
            biasC[m][0] = v0.x + v1.x; biasC[m][1] = v0.y + v1.y;
            biasC[m][2] = v0.z + v1.z; biasC[m][3] = v0.w + v1.w;
        }
        // prologue: stage chunk 0
#pragma unroll
        for (int s = 0; s < CS; ++s) {
            const float* xp = xl + s * Fn;
            xr[s][0] = *reinterpret_cast<const float4*>(xp);
            xr[s][1] = *reinterpret_cast<const float4*>(xp + 4);
            xr[s][2] = *reinterpret_cast<const float4*>(xp + 32);
            xr[s][3] = *reinterpret_cast<const float4*>(xp + 36);
        }
    }

    // ================= consumer-side state =================
    half4 WhhHi[4];
#pragma unroll
    for (int m = 0; m < 4; ++m) {
        float4 w = *reinterpret_cast<const float4*>(Whh + (m * 16 + l15) * Hn + lhi * 4);
        WhhHi[m][0] = (_Float16)w.x; WhhHi[m][1] = (_Float16)w.y;
        WhhHi[m][2] = (_Float16)w.z; WhhHi[m][3] = (_Float16)w.w;
    }

    f32x4 cstA = { 0, 0, 0, 0 }, cstB = { 0, 0, 0, 0 };
    half4 hA = { 0, 0, 0, 0 },   hB = { 0, 0, 0, 0 };
    float hcA[4] = { 0, 0, 0, 0 }, hcB[4] = { 0, 0, 0, 0 };

    auto recur = [&](const f32x4 (&g)[4], half4& hh, f32x4& cs, float (&hc)[4]) {
        f32x4 pre[4];
#pragma unroll
        for (int m = 0; m < 4; ++m)
            pre[m] = __builtin_amdgcn_mfma_f32_16x16x16f16(WhhHi[m], hh, g[m], 0, 0, 0);
#pragma unroll
        for (int r = 0; r < 4; ++r) {
            float ig = sigm(pre[0][r]);
            float fg = sigm(pre[1][r]);
            float gg = tanhp(pre[2][r]);
            float og = sigm(pre[3][r]);
            cs[r] = fmaf(fg, cs[r], ig * gg);
            hc[r] = og * tanhp(cs[r]);
        }
#pragma unroll
        for (int r = 0; r < 4; ++r)
            hh[r] = (_Float16)hc[r];
    };

    // ================= pipelined main loop =================
#pragma unroll 1
    for (int i = 0; i <= NCH; ++i) {
        if (wave >= 1) {
            // ---- producer: compute chunk i; reload xr[s] (chunk i+1) right
            //      after consuming it, so loads drain under compute.
            if (i < NCH) {
                const int bi  = i & 1;
                const int cnx = (i + 1 < NCH) ? i + 1 : NCH - 1;   // clamp
#pragma unroll
                for (int s = 0; s < CS; ++s) {
                    half8 f0 = to_half8(xr[s][0], xr[s][1]);
                    half8 f1 = to_half8(xr[s][2], xr[s][3]);
                    const float* xp = xl + (size_t)(cnx * CS + s) * Fn;
                    xr[s][0] = *reinterpret_cast<const float4*>(xp);
                    xr[s][1] = *reinterpret_cast<const float4*>(xp + 4);
                    xr[s][2] = *reinterpret_cast<const float4*>(xp + 32);
                    xr[s][3] = *reinterpret_cast<const float4*>(xp + 36);
#pragma unroll
                    for (int m = 0; m < 4; ++m) {
                        f32x4 acc = __builtin_amdgcn_mfma_f32_16x16x32_f16(
                            WihF[m][0], f0, biasC[m], 0, 0, 0);
                        acc = __builtin_amdgcn_mfma_f32_16x16x32_f16(
                            WihF[m][1], f1, acc, 0, 0, 0);
                        gxbuf[pg][bi][s][m][lane] = acc;
                    }
                }
            }
        } else if (i >= 1) {
            // ---- consumer: chunk i-1, two interleaved chains
            const int bi = (i - 1) & 1;
            f32x4 gq[2][2][4];   // [parity][group][m] — static after unroll
#pragma unroll
            for (int m = 0; m < 4; ++m) {
                gq[0][0][m] = gxbuf[0][bi][0][m][lane];
                gq[0][1][m] = gxbuf[1][bi][0][m][lane];
            }
#pragma unroll
            for (int s = 0; s < CS; ++s) {
                const int cur = s & 1, nxt = cur ^ 1;
                if (s + 1 < CS) {
#pragma unroll
                    for (int m = 0; m < 4; ++m) {
                        gq[nxt][0][m] = gxbuf[0][bi][s + 1][m][lane];
                        gq[nxt][1][m] = gxbuf[1][bi][s + 1][m][lane];
                    }
                }
                recur(gq[cur][0], hA, cstA, hcA);
                recur(gq[cur][1], hB, cstB, hcB);
            }
        }
        __syncthreads();
    }

    // ================= epilogue: Linear(16->1) + sigmoid =================
    if (wave == 0) {
        float4 wo = *reinterpret_cast<const float4*>(Wout + lhi * 4);
        float poA = hcA[0] * wo.x;
        poA = fmaf(hcA[1], wo.y, poA);
        poA = fmaf(hcA[2], wo.z, poA);
        poA = fmaf(hcA[3], wo.w, poA);
        float poB = hcB[0] * wo.x;
        poB = fmaf(hcB[1], wo.y, poB);
        poB = fmaf(hcB[2], wo.z, poB);
        poB = fmaf(hcB[3], wo.w, poB);
        poA += __shfl_xor(poA, 16);
        poA += __shfl_xor(poA, 32);
        poB += __shfl_xor(poB, 16);
        poB += __shfl_xor(poB, 32);
        if (lhi == 0) {
            out[bbase + l15]      = sigm(poA + bout[0]);
            out[bbase + 16 + l15] = sigm(poB + bout[0]);
        }
    }
}

extern "C" void kernel_launch(void* const* d_in, const int* in_sizes, int n_in,
                              void* d_out, int out_size, void* d_ws, size_t ws_size,
                              hipStream_t stream) {
    const float* x    = (const float*)d_in[0];
    const float* Wih  = (const float*)d_in[1];
    const float* Whh  = (const float*)d_in[2];
    const float* bih  = (const float*)d_in[3];
    const float* bhh  = (const float*)d_in[4];
    const float* Wout = (const float*)d_in[5];
    const float* bout = (const float*)d_in[6];
    float* out = (float*)d_out;

    lstm_fused<<<dim3(Bsz / 32), dim3(192), 0, stream>>>(
        x, Wih, Whh, bih, bhh, Wout, bout, out);
}

// Round 9
// 72.700 us; speedup vs baseline: 1.7572x; 1.7572x over previous
//
#include <hip/hip_runtime.h>

// Fused LSTM: B=4096, T=200, F=64, H=16, O=1.
// R7 structure (best: 73.7us) + ONE change: raw LDS-only barrier.
// __syncthreads() emits s_waitcnt vmcnt(0) lgkmcnt(0) + s_barrier, forcing
// producers to drain ALL in-flight HBM loads (register-targeted!) at every
// chunk barrier. Only the ds_writes need visibility -> barrier is now
// sched_barrier(0) + s_waitcnt lgkmcnt(0) + s_barrier + sched_barrier(0).
// Producer x-loads float across the barrier and drain at their use next
// chunk (counted vmcnt, T4-style).
//
// Producer/consumer, 3 waves/block (1 consumer + 2 producers), 16 batches/block.
//   pre^T(64x16) = Wih(64x64) @ x_t^T + Whh(64x16) @ h^T + bias
// Producers: input projection on MFMA (bias in C), 4 steps each per 8-step
// chunk, register-staged x reloaded per-step during compute, gx f32x4 tiles
// -> 3-deep LDS ring. Consumer: per step one mfma_16x16x16f16(WhhHi,hHi,gx)
// + lane-local cell update; gate-type m = D-tile m so each lane holds
// i,f,g,o of the SAME 4 (batch,unit) pairs and its h[4] is directly the
// next step's recurrence B-fragment -> zero cross-lane ops in the chain.

#define Bsz 4096
#define Tn  200
#define Fn  64
#define Hn  16
#define CS  8     // steps per chunk
#define NCH 25    // chunks (25*8 = 200)

typedef _Float16 half8  __attribute__((ext_vector_type(8)));
typedef _Float16 half4  __attribute__((ext_vector_type(4)));
typedef float    f32x4  __attribute__((ext_vector_type(4)));

__device__ __forceinline__ half8 to_half8(const float4& a, const float4& b) {
    half8 h;
    h[0] = (_Float16)a.x; h[1] = (_Float16)a.y; h[2] = (_Float16)a.z; h[3] = (_Float16)a.w;
    h[4] = (_Float16)b.x; h[5] = (_Float16)b.y; h[6] = (_Float16)b.z; h[7] = (_Float16)b.w;
    return h;
}

__device__ __forceinline__ float sigm(float z) {
    return __builtin_amdgcn_rcpf(1.0f + __builtin_amdgcn_exp2f(z * -1.4426950408889634f));
}
__device__ __forceinline__ float tanhp(float z) {
    return fmaf(2.0f, __builtin_amdgcn_rcpf(
        1.0f + __builtin_amdgcn_exp2f(z * -2.8853900817779268f)), -1.0f);
}

// LDS-visibility-only barrier: does NOT drain vmcnt (global loads to regs
// may float across). sched_barrier(0) pins memory ops on both sides.
__device__ __forceinline__ void lds_barrier() {
    __builtin_amdgcn_sched_barrier(0);
    asm volatile("s_waitcnt lgkmcnt(0)" ::: "memory");
    __builtin_amdgcn_s_barrier();
    __builtin_amdgcn_sched_barrier(0);
}

__global__ __launch_bounds__(192, 1) void lstm_fused(
    const float* __restrict__ x,     // [B, T, F]
    const float* __restrict__ Wih,   // [64, 64]
    const float* __restrict__ Whh,   // [64, 16]
    const float* __restrict__ bih,   // [64]
    const float* __restrict__ bhh,   // [64]
    const float* __restrict__ Wout,  // [1, 16]
    const float* __restrict__ bout,  // [1]
    float* __restrict__ out)         // [B, 1]
{
    const int lane = threadIdx.x & 63;
    const int wave = threadIdx.x >> 6;   // 0 = consumer, 1/2 = producers
    const int l15  = lane & 15;
    const int lhi  = lane >> 4;
    const int b    = (int)blockIdx.x * 16 + l15;   // per-lane batch

    // gx ring: [buf][step][gate-tile m][lane] f32x4 = 3*8*4*64*16 B = 96 KiB
    __shared__ f32x4 gxbuf[3][CS][4][64];

    // ================= producer-side state =================
    half8 WihF[4][2];
    f32x4 biasC[4];
    float4 xr[4][4];                       // 4 staged steps per producer
    const int pofs = (wave - 1) * 4;       // this producer's step offset
    const float* xl = x + (size_t)b * (Tn * Fn) + lhi * 8;

    if (wave >= 1) {
#pragma unroll
        for (int m = 0; m < 4; ++m)
#pragma unroll
            for (int kh = 0; kh < 2; ++kh) {
                const float* wr = Wih + (m * 16 + l15) * Fn + kh * 32 + lhi * 8;
                float4 w0 = *reinterpret_cast<const float4*>(wr);
                float4 w1 = *reinterpret_cast<const float4*>(wr + 4);
                WihF[m][kh] = to_half8(w0, w1);
            }
#pragma unroll
        for (int m = 0; m < 4; ++m) {
            float4 v0 = *reinterpret_cast<const float4*>(bih + m * 16 + lhi * 4);
            float4 v1 = *reinterpret_cast<const float4*>(bhh + m * 16 + lhi * 4);
            biasC[m][0] = v0.x + v1.x; biasC[m][1] = v0.y + v1.y;
            biasC[m][2] = v0.z + v1.z; biasC[m][3] = v0.w + v1.w;
        }
        // prologue: stage my 4 steps of chunk 0
#pragma unroll
        for (int s = 0; s < 4; ++s) {
            const float* xp = xl + (pofs + s) * Fn;
            xr[s][0] = *reinterpret_cast<const float4*>(xp);
            xr[s][1] = *reinterpret_cast<const float4*>(xp + 4);
            xr[s][2] = *reinterpret_cast<const float4*>(xp + 32);
            xr[s][3] = *reinterpret_cast<const float4*>(xp + 36);
        }
    }

    // ================= consumer-side state =================
    half4 WhhHi[4];
#pragma unroll
    for (int m = 0; m < 4; ++m) {
        float4 w = *reinterpret_cast<const float4*>(Whh + (m * 16 + l15) * Hn + lhi * 4);
        WhhHi[m][0] = (_Float16)w.x; WhhHi[m][1] = (_Float16)w.y;
        WhhHi[m][2] = (_Float16)w.z; WhhHi[m][3] = (_Float16)w.w;
    }

    f32x4 cst = { 0.0f, 0.0f, 0.0f, 0.0f };
    half4 hHi = { 0, 0, 0, 0 };
    float hcur[4] = { 0.0f, 0.0f, 0.0f, 0.0f };

    // one recurrence + cell step consuming gx tiles g[0..3]
    auto recur = [&](f32x4 (&g)[4]) {
        f32x4 pre[4];
#pragma unroll
        for (int m = 0; m < 4; ++m)
            pre[m] = __builtin_amdgcn_mfma_f32_16x16x16f16(WhhHi[m], hHi, g[m], 0, 0, 0);
#pragma unroll
        for (int r = 0; r < 4; ++r) {
            float ig = sigm(pre[0][r]);
            float fg = sigm(pre[1][r]);
            float gg = tanhp(pre[2][r]);
            float og = sigm(pre[3][r]);
            cst[r]  = fmaf(fg, cst[r], ig * gg);
            hcur[r] = og * tanhp(cst[r]);
        }
#pragma unroll
        for (int r = 0; r < 4; ++r)
            hHi[r] = (_Float16)hcur[r];
    };

    // ================= pipelined main loop =================
#pragma unroll 1
    for (int i = 0; i < NCH + 2; ++i) {
        lds_barrier();
        if (wave >= 1) {
            // ---- producers: compute my 4 steps of chunk i; reload xr[s]
            //      (chunk i+1) right after consuming it
            if (i < NCH) {
                const int bi  = i % 3;
                const int cnx = (i + 1 < NCH) ? i + 1 : NCH - 1;   // clamp
#pragma unroll
                for (int s = 0; s < 4; ++s) {
                    half8 f0 = to_half8(xr[s][0], xr[s][1]);
                    half8 f1 = to_half8(xr[s][2], xr[s][3]);
                    const float* xp = xl + (size_t)(cnx * CS + pofs + s) * Fn;
                    xr[s][0] = *reinterpret_cast<const float4*>(xp);
                    xr[s][1] = *reinterpret_cast<const float4*>(xp + 4);
                    xr[s][2] = *reinterpret_cast<const float4*>(xp + 32);
                    xr[s][3] = *reinterpret_cast<const float4*>(xp + 36);
#pragma unroll
                    for (int m = 0; m < 4; ++m) {
                        f32x4 acc = __builtin_amdgcn_mfma_f32_16x16x32_f16(
                            WihF[m][0], f0, biasC[m], 0, 0, 0);
                        acc = __builtin_amdgcn_mfma_f32_16x16x32_f16(
                            WihF[m][1], f1, acc, 0, 0, 0);
                        gxbuf[bi][pofs + s][m][lane] = acc;
                    }
                }
            }
        } else {
            // ---- consumer: recurrence over chunk i-2
            if (i >= 2) {
                const int bi = (i - 2) % 3;
                f32x4 gA[4], gB[4];
#pragma unroll
                for (int m = 0; m < 4; ++m) gA[m] = gxbuf[bi][0][m][lane];
#pragma unroll
                for (int m = 0; m < 4; ++m) gB[m] = gxbuf[bi][1][m][lane];
                recur(gA);
#pragma unroll
                for (int m = 0; m < 4; ++m) gA[m] = gxbuf[bi][2][m][lane];
                recur(gB);
#pragma unroll
                for (int m = 0; m < 4; ++m) gB[m] = gxbuf[bi][3][m][lane];
                recur(gA);
#pragma unroll
                for (int m = 0; m < 4; ++m) gA[m] = gxbuf[bi][4][m][lane];
                recur(gB);
#pragma unroll
                for (int m = 0; m < 4; ++m) gB[m] = gxbuf[bi][5][m][lane];
                recur(gA);
#pragma unroll
                for (int m = 0; m < 4; ++m) gA[m] = gxbuf[bi][6][m][lane];
                recur(gB);
#pragma unroll
                for (int m = 0; m < 4; ++m) gB[m] = gxbuf[bi][7][m][lane];
                recur(gA);
                recur(gB);
            }
        }
    }

    // ================= epilogue: Linear(16->1) + sigmoid =================
    if (wave == 0) {
        float4 wo = *reinterpret_cast<const float4*>(Wout + lhi * 4);
        float po = hcur[0] * wo.x;
        po = fmaf(hcur[1], wo.y, po);
        po = fmaf(hcur[2], wo.z, po);
        po = fmaf(hcur[3], wo.w, po);
        po += __shfl_xor(po, 16);
        po += __shfl_xor(po, 32);
        if (lhi == 0)
            out[b] = sigm(po + bout[0]);
    }
}

extern "C" void kernel_launch(void* const* d_in, const int* in_sizes, int n_in,
                              void* d_out, int out_size, void* d_ws, size_t ws_size,
                              hipStream_t stream) {
    const float* x    = (const float*)d_in[0];
    const float* Wih  = (const float*)d_in[1];
    const float* Whh  = (const float*)d_in[2];
    const float* bih  = (const float*)d_in[3];
    const float* bhh  = (const float*)d_in[4];
    const float* Wout = (const float*)d_in[5];
    const float* bout = (const float*)d_in[6];
    float* out = (float*)d_out;

    lstm_fused<<<dim3(Bsz / 16), dim3(192), 0, stream>>>(
        x, Wih, Whh, bih, bhh, Wout, bout, out);
}